// Round 16
// baseline (50.009 us; speedup 1.0000x reference)
//
#include <hip/hip_runtime.h>
#include <math.h>

#define BB 256
#define NN 1024
#define DD 128
#define NCHUNK 4
#define ROWS (NN / NCHUNK)   // 256

// workspace layout (in floats)
#define PA_OFF   0
#define PCI_OFF  (NCHUNK*BB*DD)            // 131072
#define PCJ_OFF  (2*NCHUNK*BB*DD)          // 262144
#define PCNT_OFF (3*NCHUNK*BB*DD)          // 393216
#define U0_OFF   (PCNT_OFF + NCHUNK*BB)    // 394240
#define V0_OFF   (U0_OFF + BB*DD)          // 427008
#define U1_OFF   (V0_OFF + BB*DD)          // 459776
#define V1_OFF   (U1_OFF + BB*DD)          // 492544
// total = 525312 floats = 2.10 MB

typedef _Float16 f16x8 __attribute__((ext_vector_type(8)));
typedef float    f32x4 __attribute__((ext_vector_type(4)));

// ---------------------------------------------------------------------------
// Fused kernel, XCD-mixed roles: 4096 blocks = 3072 k1 + 1024 k2.
// r15's idx%4==1 selector put ALL k2 blocks on XCDs 1,5 (idx%8 ∈ {1,5}) --
// an accidental spatial partition that capped k1 at 192 CUs' worth of
// per-CU-saturated (24.7 GB/s) bandwidth. New selector (x+g)%8 ∈ {0,4}
// (x=idx&7, g=idx>>3) keeps the exact 1:3 ratio but rotates k2 blocks
// uniformly across all 8 XCDs, so k1's mandatory 192 MB stream uses all
// 256 CUs' memory paths while k2's MFMA + L2 reads hide beneath it.
//
// k1 role (r9-exact body, aliased LDS): sparse masked streaming reductions.
//   role 0: P_A = sum_n (mi-mj)*d ; 1: P_Ci = sum_n mi*si ; 2: P_Cj = mj*sj
// k2 role: 64b x 64c MFMA tile of M = relu(dm@W1+b1), fused w2 contraction.
//   Bs (W1 c-half, f16, transposed [c][k]) = 17.4 KB LDS (the only LDS).
//   A-frags: per-lane direct global loads from d[:,0,:] (L2-resident) + cvt.
//   c-half partials go to U0/V0 or U1/V1; k3 sums.
// ---------------------------------------------------------------------------
__global__ __launch_bounds__(256) void fused_k12(
    const float* __restrict__ d, const float* __restrict__ si,
    const float* __restrict__ sj, const void* __restrict__ miv,
    const void* __restrict__ mjv, const float* __restrict__ W1,
    const float* __restrict__ b1, const float* __restrict__ W2,
    float* __restrict__ ws)
{
    const int idx = blockIdx.x;
    const int t   = threadIdx.x;

    // one shared buffer, aliased per role (prevents LDS sum-blowup)
    __shared__ __align__(16) char smem[17408];

    // ---- XCD-uniform role selection (bijective) ----
    const int g  = idx >> 3;            // 0..511
    const int x  = idx & 7;             // XCD under round-robin dispatch
    const int xa = (8 - (g & 7)) & 7;   // k2 slot A for this group
    const int xb = (xa + 4) & 7;        // k2 slot B
    const bool is_k2 = (x == xa) || (x == xb);

    if (is_k2) {
        // =================== k2 role (MFMA) ===================
        const int k2id  = g * 2 + (x == xb ? 1 : 0);   // 0..1023
        const int ctile = k2id & 255;      // 256 c-tiles = 128 p x 2 halves
        const int bg    = k2id >> 8;       // 0..3
        const int p     = ctile >> 1;
        const int chalf = ctile & 1;
        const int c0b   = chalf * 64;
        const int b0    = bg * 64;
        const int wid   = t >> 6;          // wave 0..3
        const int lane  = t & 63;
        const int lcol  = lane & 15;
        const int lrow  = lane >> 4;

        _Float16 (*Bs)[136] = (_Float16(*)[136])smem;   // [c][k] 17408 B

        // stage B transposed: W1[k][p*128 + c0b + c] -> Bs[c][k], f32->f16
        for (int s = t; s < 128 * 16; s += 256) {
            const int k  = s >> 4;
            const int c4 = (s & 15) * 4;
            const float4 v =
                *(const float4*)(W1 + (size_t)k * 16384 + p * 128 + c0b + c4);
            Bs[c4 + 0][k] = (_Float16)v.x;
            Bs[c4 + 1][k] = (_Float16)v.y;
            Bs[c4 + 2][k] = (_Float16)v.z;
            Bs[c4 + 3][k] = (_Float16)v.w;
        }
        __syncthreads();

        // A rows direct from global (d[:,0,:] is 128 KB, L2-resident)
        const int brow = b0 + wid * 16 + lcol;
        const float* drow = d + (size_t)brow * (NN * DD);

        f32x4 acc[4];
        #pragma unroll
        for (int n = 0; n < 4; ++n) acc[n] = (f32x4){0.f, 0.f, 0.f, 0.f};

        #pragma unroll
        for (int ks = 0; ks < 4; ++ks) {
            const int kf = ks * 32 + lrow * 8;
            const float4 a0 = *(const float4*)(drow + kf);
            const float4 a1 = *(const float4*)(drow + kf + 4);
            f16x8 afrag;
            afrag[0] = (_Float16)a0.x; afrag[1] = (_Float16)a0.y;
            afrag[2] = (_Float16)a0.z; afrag[3] = (_Float16)a0.w;
            afrag[4] = (_Float16)a1.x; afrag[5] = (_Float16)a1.y;
            afrag[6] = (_Float16)a1.z; afrag[7] = (_Float16)a1.w;
            #pragma unroll
            for (int n = 0; n < 4; ++n) {
                const f16x8 bfrag = *(const f16x8*)&Bs[n * 16 + lcol][kf];
                acc[n] = __builtin_amdgcn_mfma_f32_16x16x32_f16(
                    afrag, bfrag, acc[n], 0, 0, 0);
            }
        }

        // epilogue: relu+bias, contract c with w2a/w2b (verified C/D layout:
        // col=lane&15, row=(lane>>4)*4+reg)
        float ua[4] = {0.f, 0.f, 0.f, 0.f};
        float va[4] = {0.f, 0.f, 0.f, 0.f};
        #pragma unroll
        for (int n = 0; n < 4; ++n) {
            const int c = c0b + n * 16 + lcol;
            const float bias = b1[p * 128 + c];
            const float w2a  = W2[c];
            const float w2b  = W2[128 + c];
            #pragma unroll
            for (int reg = 0; reg < 4; ++reg) {
                const float g2 = fmaxf(acc[n][reg] + bias, 0.f);
                ua[reg] = fmaf(g2, w2a, ua[reg]);
                va[reg] = fmaf(g2, w2b, va[reg]);
            }
        }
        #pragma unroll
        for (int off = 8; off > 0; off >>= 1) {
            #pragma unroll
            for (int reg = 0; reg < 4; ++reg) {
                ua[reg] += __shfl_xor(ua[reg], off, 64);
                va[reg] += __shfl_xor(va[reg], off, 64);
            }
        }
        if (lcol == 0) {
            const size_t uo = chalf ? U1_OFF : U0_OFF;
            const size_t vo = chalf ? V1_OFF : V0_OFF;
            #pragma unroll
            for (int reg = 0; reg < 4; ++reg) {
                const int b = b0 + wid * 16 + lrow * 4 + reg;
                ws[uo + (size_t)b * DD + p] = ua[reg];
                ws[vo + (size_t)b * DD + p] = va[reg];
            }
        }
        return;
    }

    // =================== k1 role (r9-exact body, aliased LDS) ===============
    // rank of x among the 6 non-k2 slots of this group
    const int rank = x - (xa < x ? 1 : 0) - (xb < x ? 1 : 0);
    const int k1id  = g * 6 + rank;          // 0..3071
    const int chunk = k1id & 3;
    const int b     = (k1id >> 2) & 255;
    const int role  = k1id >> 10;
    const int lane  = t & 31;   // float4 column group: cols lane*4 .. +3
    const int rg    = t >> 5;   // row group 0..7
    const int wid   = t >> 6;   // wave 0..3
    const int l64   = t & 63;

    // aliased LDS layout inside smem (total 6720 B <= 17408)
    float* s_wc   = (float*)smem;              // [256]  @0
    short* s_idx  = (short*)(smem + 1024);     // [256]  @1024
    int*   s_wcnt = (int*)(smem + 1536);       // [4]
    int*   s_woff = (int*)(smem + 1552);       // [5]
    int*   s_cnt4 = (int*)(smem + 1572);       // [4]
    int*   s_mode = (int*)(smem + 1588);       // [1]
    float (*red)[5] = (float(*)[5])(smem + 1600);  // [256][5]

    // ---- mask dtype auto-detect (bool bytes vs int32) ----
    if (t == 0) *s_mode = 0;
    __syncthreads();
    {
        const unsigned int* a = (const unsigned int*)miv;
        const unsigned int* c = (const unsigned int*)mjv;
        if ((a[t] | c[t]) > 1u) *s_mode = 1;  // bytes of 0/1 packed in a word
    }
    __syncthreads();
    const bool bytes_mode = (*s_mode != 0);

    const int    n0      = chunk * ROWS;
    const size_t rowbase = (size_t)b * NN;

    float w;
    {
        const size_t m = rowbase + (size_t)(n0 + t);
        float fi, fj;
        if (bytes_mode) {
            fi = (float)((const unsigned char*)miv)[m];
            fj = (float)((const unsigned char*)mjv)[m];
        } else {
            fi = (float)((const int*)miv)[m];
            fj = (float)((const int*)mjv)[m];
        }
        w = (role == 0) ? (fi - fj) : ((role == 1) ? fi : fj);
        if (role == 0) {
            const unsigned long long bi = __ballot(fi != 0.f);
            const unsigned long long bj = __ballot(fj != 0.f);
            if (l64 == 0) s_cnt4[wid] = __popcll(bi) - __popcll(bj);
        }
    }
    const bool keep = (w != 0.f);
    const unsigned long long ball = __ballot(keep);
    const int prefix = __popcll(ball & ((1ull << l64) - 1ull));
    if (l64 == 0) s_wcnt[wid] = __popcll(ball);
    __syncthreads();
    if (t == 0) {
        int a0 = 0;
        #pragma unroll
        for (int ww = 0; ww < 4; ++ww) { s_woff[ww] = a0; a0 += s_wcnt[ww]; }
        s_woff[4] = a0;
        if (role == 0)
            ws[PCNT_OFF + chunk * BB + b] =
                (float)(s_cnt4[0] + s_cnt4[1] + s_cnt4[2] + s_cnt4[3]);
    }
    __syncthreads();
    const int K    = s_woff[4];
    const int Kpad = (K + 31) & ~31;
    if (keep) {
        const int pos = s_woff[wid] + prefix;
        s_idx[pos] = (short)t;
        s_wc[pos]  = w;
    }
    for (int p = K + t; p < Kpad; p += 256) { s_idx[p] = 0; s_wc[p] = 0.f; }
    __syncthreads();

    const float* src = (role == 0) ? d : ((role == 1) ? si : sj);
    const size_t cbase = (rowbase + (size_t)n0) * (size_t)DD
                       + (size_t)lane * 4;

    float acc[4] = {0.f, 0.f, 0.f, 0.f};

    for (int i = 0; i < Kpad; i += 32) {
        int   r[4];
        float wv[4];
        #pragma unroll
        for (int u = 0; u < 4; ++u) {
            const int p = i + u * 8 + rg;
            r[u]  = s_idx[p];      // broadcast within row-group
            wv[u] = s_wc[p];
        }
        float4 v[4];
        #pragma unroll
        for (int u = 0; u < 4; ++u)
            v[u] = *(const float4*)(src + cbase + (size_t)r[u] * DD);
        #pragma unroll
        for (int u = 0; u < 4; ++u) {
            acc[0] = fmaf(wv[u], v[u].x, acc[0]);
            acc[1] = fmaf(wv[u], v[u].y, acc[1]);
            acc[2] = fmaf(wv[u], v[u].z, acc[2]);
            acc[3] = fmaf(wv[u], v[u].w, acc[3]);
        }
    }

    // ---- reduce the 8 row-groups (t strides of 32); [5] breaks bank stride
    #pragma unroll
    for (int i = 0; i < 4; ++i) red[t][i] = acc[i];
    __syncthreads();
    if (t < 128) {
        #pragma unroll
        for (int i = 0; i < 4; ++i) red[t][i] += red[t + 128][i];
    }
    __syncthreads();
    if (t < 64) {
        #pragma unroll
        for (int i = 0; i < 4; ++i) red[t][i] += red[t + 64][i];
    }
    __syncthreads();
    if (t < 32) {
        #pragma unroll
        for (int i = 0; i < 4; ++i) red[t][i] += red[t + 32][i];
        const size_t poff = ((role == 0) ? PA_OFF : ((role == 1) ? PCI_OFF
                                                                 : PCJ_OFF))
                          + ((size_t)chunk * BB + b) * DD;
        float* P = ws + poff;
        #pragma unroll
        for (int i = 0; i < 4; ++i) P[t * 4 + i] = red[t][i];
    }
}

// ---------------------------------------------------------------------------
// Kernel 3: per-batch score assembly + sigmoid.
//   out[b] = sigmoid( Adiff·(u0+u1) + (Ci-Cj)·(v0+v1) + b2*cntdiff )
// grid = 256, block = 64 (one wave per batch).
// ---------------------------------------------------------------------------
__global__ __launch_bounds__(64) void k3_final(
    const float* __restrict__ ws, const float* __restrict__ b2p,
    float* __restrict__ out)
{
    const int b = blockIdx.x;
    const int l = threadIdx.x;

    float s = 0.f;
    #pragma unroll
    for (int rep = 0; rep < 2; ++rep) {
        const int k = l + rep * 64;
        float A = 0.f, Ci = 0.f, Cj = 0.f;
        #pragma unroll
        for (int c = 0; c < NCHUNK; ++c) {
            A  += ws[PA_OFF  + ((size_t)c * BB + b) * DD + k];
            Ci += ws[PCI_OFF + ((size_t)c * BB + b) * DD + k];
            Cj += ws[PCJ_OFF + ((size_t)c * BB + b) * DD + k];
        }
        const float u = ws[U0_OFF + (size_t)b * DD + k]
                      + ws[U1_OFF + (size_t)b * DD + k];
        const float v = ws[V0_OFF + (size_t)b * DD + k]
                      + ws[V1_OFF + (size_t)b * DD + k];
        s += A * u + (Ci - Cj) * v;
    }
    #pragma unroll
    for (int off = 32; off > 0; off >>= 1) s += __shfl_down(s, off, 64);

    if (l == 0) {
        float cnt = 0.f;
        #pragma unroll
        for (int c = 0; c < NCHUNK; ++c) cnt += ws[PCNT_OFF + c * BB + b];
        const float score = s + b2p[0] * cnt;   // SCALING_FACTOR == 1.0
        out[b] = 1.f / (1.f + expf(-score));
    }
}

extern "C" void kernel_launch(void* const* d_in, const int* in_sizes, int n_in,
                              void* d_out, int out_size, void* d_ws, size_t ws_size,
                              hipStream_t stream)
{
    const float* d   = (const float*)d_in[0];
    const float* si  = (const float*)d_in[1];
    const float* sj  = (const float*)d_in[2];
    const void*  mi  = d_in[3];
    const void*  mj  = d_in[4];
    const float* W1  = (const float*)d_in[5];
    const float* b1  = (const float*)d_in[6];
    const float* W2  = (const float*)d_in[7];
    const float* b2  = (const float*)d_in[8];
    float* ws  = (float*)d_ws;
    float* out = (float*)d_out;

    fused_k12<<<4096, 256, 0, stream>>>(d, si, sj, mi, mj, W1, b1, W2, ws);
    k3_final<<<BB, 64, 0, stream>>>(ws, b2, out);
}

// Round 17
// 48.490 us; speedup vs baseline: 1.0313x; 1.0313x over previous
//
#include <hip/hip_runtime.h>
#include <math.h>

#define BB 256
#define NN 1024
#define DD 128
#define NCHUNK 4
#define ROWS (NN / NCHUNK)   // 256

// workspace layout (in floats)
#define PA_OFF   0
#define PCI_OFF  (NCHUNK*BB*DD)            // 131072
#define PCJ_OFF  (2*NCHUNK*BB*DD)          // 262144
#define PCNT_OFF (3*NCHUNK*BB*DD)          // 393216
#define U0_OFF   (PCNT_OFF + NCHUNK*BB)    // 394240
#define V0_OFF   (U0_OFF + BB*DD)          // 427008
#define U1_OFF   (V0_OFF + BB*DD)          // 459776
#define V1_OFF   (U1_OFF + BB*DD)          // 492544
// total = 525312 floats = 2.10 MB

typedef _Float16 f16x8 __attribute__((ext_vector_type(8)));
typedef float    f32x4 __attribute__((ext_vector_type(4)));

// ---------------------------------------------------------------------------
// Fused kernel, TEMPORALLY split roles: 4096 blocks = 3072 k1 THEN 1024 k2.
// r15 (spatial partition, k2 on XCDs 1&5) = 44.2 us: k1's 192 MB stream used
// only 192 CUs at the saturated 24.7 GB/s/CU rate (40.5 us). r16 (concurrent
// XCD-uniform mixing) = 50 us: k2's L2 traffic polluted all XCDs and degraded
// the stream. This round: k1 blocks occupy indices 0..3071 (round-robin over
// all 8 XCDs -> full-chip 6.3 TB/s stream phase, ~31 us); k2 blocks appended
// at 3072..4095 backfill CUs as the k1 tail drains (~4-5 us, part hidden).
//
// k1 role (r9-exact body, aliased LDS): sparse masked streaming reductions.
//   role 0: P_A = sum_n (mi-mj)*d ; 1: P_Ci = sum_n mi*si ; 2: P_Cj = mj*sj
// k2 role: 64b x 64c MFMA tile of M = relu(dm@W1+b1), fused w2 contraction.
//   Bs (W1 c-half, f16, transposed [c][k]) = 17.4 KB LDS (the only LDS).
//   A-frags: per-lane direct global loads from d[:,0,:] (L2-resident) + cvt.
//   c-half partials go to U0/V0 or U1/V1; k3 sums.
// ---------------------------------------------------------------------------
__global__ __launch_bounds__(256) void fused_k12(
    const float* __restrict__ d, const float* __restrict__ si,
    const float* __restrict__ sj, const void* __restrict__ miv,
    const void* __restrict__ mjv, const float* __restrict__ W1,
    const float* __restrict__ b1, const float* __restrict__ W2,
    float* __restrict__ ws)
{
    const int idx = blockIdx.x;
    const int t   = threadIdx.x;

    // one shared buffer, aliased per role (prevents LDS sum-blowup)
    __shared__ __align__(16) char smem[17408];

    if (idx >= 3072) {
        // =================== k2 role (MFMA), appended tail ===================
        const int k2id  = idx - 3072;      // 0..1023
        const int ctile = k2id & 255;      // 256 c-tiles = 128 p x 2 halves
        const int bg    = k2id >> 8;       // 0..3
        const int p     = ctile >> 1;
        const int chalf = ctile & 1;
        const int c0b   = chalf * 64;
        const int b0    = bg * 64;
        const int wid   = t >> 6;          // wave 0..3
        const int lane  = t & 63;
        const int lcol  = lane & 15;
        const int lrow  = lane >> 4;

        _Float16 (*Bs)[136] = (_Float16(*)[136])smem;   // [c][k] 17408 B

        // stage B transposed: W1[k][p*128 + c0b + c] -> Bs[c][k], f32->f16
        for (int s = t; s < 128 * 16; s += 256) {
            const int k  = s >> 4;
            const int c4 = (s & 15) * 4;
            const float4 v =
                *(const float4*)(W1 + (size_t)k * 16384 + p * 128 + c0b + c4);
            Bs[c4 + 0][k] = (_Float16)v.x;
            Bs[c4 + 1][k] = (_Float16)v.y;
            Bs[c4 + 2][k] = (_Float16)v.z;
            Bs[c4 + 3][k] = (_Float16)v.w;
        }
        __syncthreads();

        // A rows direct from global (d[:,0,:] is 128 KB, L2-resident)
        const int brow = b0 + wid * 16 + lcol;
        const float* drow = d + (size_t)brow * (NN * DD);

        f32x4 acc[4];
        #pragma unroll
        for (int n = 0; n < 4; ++n) acc[n] = (f32x4){0.f, 0.f, 0.f, 0.f};

        #pragma unroll
        for (int ks = 0; ks < 4; ++ks) {
            const int kf = ks * 32 + lrow * 8;
            const float4 a0 = *(const float4*)(drow + kf);
            const float4 a1 = *(const float4*)(drow + kf + 4);
            f16x8 afrag;
            afrag[0] = (_Float16)a0.x; afrag[1] = (_Float16)a0.y;
            afrag[2] = (_Float16)a0.z; afrag[3] = (_Float16)a0.w;
            afrag[4] = (_Float16)a1.x; afrag[5] = (_Float16)a1.y;
            afrag[6] = (_Float16)a1.z; afrag[7] = (_Float16)a1.w;
            #pragma unroll
            for (int n = 0; n < 4; ++n) {
                const f16x8 bfrag = *(const f16x8*)&Bs[n * 16 + lcol][kf];
                acc[n] = __builtin_amdgcn_mfma_f32_16x16x32_f16(
                    afrag, bfrag, acc[n], 0, 0, 0);
            }
        }

        // epilogue: relu+bias, contract c with w2a/w2b (verified C/D layout:
        // col=lane&15, row=(lane>>4)*4+reg)
        float ua[4] = {0.f, 0.f, 0.f, 0.f};
        float va[4] = {0.f, 0.f, 0.f, 0.f};
        #pragma unroll
        for (int n = 0; n < 4; ++n) {
            const int c = c0b + n * 16 + lcol;
            const float bias = b1[p * 128 + c];
            const float w2a  = W2[c];
            const float w2b  = W2[128 + c];
            #pragma unroll
            for (int reg = 0; reg < 4; ++reg) {
                const float g2 = fmaxf(acc[n][reg] + bias, 0.f);
                ua[reg] = fmaf(g2, w2a, ua[reg]);
                va[reg] = fmaf(g2, w2b, va[reg]);
            }
        }
        #pragma unroll
        for (int off = 8; off > 0; off >>= 1) {
            #pragma unroll
            for (int reg = 0; reg < 4; ++reg) {
                ua[reg] += __shfl_xor(ua[reg], off, 64);
                va[reg] += __shfl_xor(va[reg], off, 64);
            }
        }
        if (lcol == 0) {
            const size_t uo = chalf ? U1_OFF : U0_OFF;
            const size_t vo = chalf ? V1_OFF : V0_OFF;
            #pragma unroll
            for (int reg = 0; reg < 4; ++reg) {
                const int b = b0 + wid * 16 + lrow * 4 + reg;
                ws[uo + (size_t)b * DD + p] = ua[reg];
                ws[vo + (size_t)b * DD + p] = va[reg];
            }
        }
        return;
    }

    // =================== k1 role (r9-exact body, aliased LDS) ===============
    const int k1id  = idx;                   // 0..3071
    const int chunk = k1id & 3;
    const int b     = (k1id >> 2) & 255;
    const int role  = k1id >> 10;
    const int lane  = t & 31;   // float4 column group: cols lane*4 .. +3
    const int rg    = t >> 5;   // row group 0..7
    const int wid   = t >> 6;   // wave 0..3
    const int l64   = t & 63;

    // aliased LDS layout inside smem (total 6720 B <= 17408)
    float* s_wc   = (float*)smem;              // [256]  @0
    short* s_idx  = (short*)(smem + 1024);     // [256]  @1024
    int*   s_wcnt = (int*)(smem + 1536);       // [4]
    int*   s_woff = (int*)(smem + 1552);       // [5]
    int*   s_cnt4 = (int*)(smem + 1572);       // [4]
    int*   s_mode = (int*)(smem + 1588);       // [1]
    float (*red)[5] = (float(*)[5])(smem + 1600);  // [256][5]

    // ---- mask dtype auto-detect (bool bytes vs int32) ----
    if (t == 0) *s_mode = 0;
    __syncthreads();
    {
        const unsigned int* a = (const unsigned int*)miv;
        const unsigned int* c = (const unsigned int*)mjv;
        if ((a[t] | c[t]) > 1u) *s_mode = 1;  // bytes of 0/1 packed in a word
    }
    __syncthreads();
    const bool bytes_mode = (*s_mode != 0);

    const int    n0      = chunk * ROWS;
    const size_t rowbase = (size_t)b * NN;

    float w;
    {
        const size_t m = rowbase + (size_t)(n0 + t);
        float fi, fj;
        if (bytes_mode) {
            fi = (float)((const unsigned char*)miv)[m];
            fj = (float)((const unsigned char*)mjv)[m];
        } else {
            fi = (float)((const int*)miv)[m];
            fj = (float)((const int*)mjv)[m];
        }
        w = (role == 0) ? (fi - fj) : ((role == 1) ? fi : fj);
        if (role == 0) {
            const unsigned long long bi = __ballot(fi != 0.f);
            const unsigned long long bj = __ballot(fj != 0.f);
            if (l64 == 0) s_cnt4[wid] = __popcll(bi) - __popcll(bj);
        }
    }
    const bool keep = (w != 0.f);
    const unsigned long long ball = __ballot(keep);
    const int prefix = __popcll(ball & ((1ull << l64) - 1ull));
    if (l64 == 0) s_wcnt[wid] = __popcll(ball);
    __syncthreads();
    if (t == 0) {
        int a0 = 0;
        #pragma unroll
        for (int ww = 0; ww < 4; ++ww) { s_woff[ww] = a0; a0 += s_wcnt[ww]; }
        s_woff[4] = a0;
        if (role == 0)
            ws[PCNT_OFF + chunk * BB + b] =
                (float)(s_cnt4[0] + s_cnt4[1] + s_cnt4[2] + s_cnt4[3]);
    }
    __syncthreads();
    const int K    = s_woff[4];
    const int Kpad = (K + 31) & ~31;
    if (keep) {
        const int pos = s_woff[wid] + prefix;
        s_idx[pos] = (short)t;
        s_wc[pos]  = w;
    }
    for (int p = K + t; p < Kpad; p += 256) { s_idx[p] = 0; s_wc[p] = 0.f; }
    __syncthreads();

    const float* src = (role == 0) ? d : ((role == 1) ? si : sj);
    const size_t cbase = (rowbase + (size_t)n0) * (size_t)DD
                       + (size_t)lane * 4;

    float acc[4] = {0.f, 0.f, 0.f, 0.f};

    for (int i = 0; i < Kpad; i += 32) {
        int   r[4];
        float wv[4];
        #pragma unroll
        for (int u = 0; u < 4; ++u) {
            const int p = i + u * 8 + rg;
            r[u]  = s_idx[p];      // broadcast within row-group
            wv[u] = s_wc[p];
        }
        float4 v[4];
        #pragma unroll
        for (int u = 0; u < 4; ++u)
            v[u] = *(const float4*)(src + cbase + (size_t)r[u] * DD);
        #pragma unroll
        for (int u = 0; u < 4; ++u) {
            acc[0] = fmaf(wv[u], v[u].x, acc[0]);
            acc[1] = fmaf(wv[u], v[u].y, acc[1]);
            acc[2] = fmaf(wv[u], v[u].z, acc[2]);
            acc[3] = fmaf(wv[u], v[u].w, acc[3]);
        }
    }

    // ---- reduce the 8 row-groups (t strides of 32); [5] breaks bank stride
    #pragma unroll
    for (int i = 0; i < 4; ++i) red[t][i] = acc[i];
    __syncthreads();
    if (t < 128) {
        #pragma unroll
        for (int i = 0; i < 4; ++i) red[t][i] += red[t + 128][i];
    }
    __syncthreads();
    if (t < 64) {
        #pragma unroll
        for (int i = 0; i < 4; ++i) red[t][i] += red[t + 64][i];
    }
    __syncthreads();
    if (t < 32) {
        #pragma unroll
        for (int i = 0; i < 4; ++i) red[t][i] += red[t + 32][i];
        const size_t poff = ((role == 0) ? PA_OFF : ((role == 1) ? PCI_OFF
                                                                 : PCJ_OFF))
                          + ((size_t)chunk * BB + b) * DD;
        float* P = ws + poff;
        #pragma unroll
        for (int i = 0; i < 4; ++i) P[t * 4 + i] = red[t][i];
    }
}

// ---------------------------------------------------------------------------
// Kernel 3: per-batch score assembly + sigmoid.
//   out[b] = sigmoid( Adiff·(u0+u1) + (Ci-Cj)·(v0+v1) + b2*cntdiff )
// grid = 256, block = 64 (one wave per batch).
// ---------------------------------------------------------------------------
__global__ __launch_bounds__(64) void k3_final(
    const float* __restrict__ ws, const float* __restrict__ b2p,
    float* __restrict__ out)
{
    const int b = blockIdx.x;
    const int l = threadIdx.x;

    float s = 0.f;
    #pragma unroll
    for (int rep = 0; rep < 2; ++rep) {
        const int k = l + rep * 64;
        float A = 0.f, Ci = 0.f, Cj = 0.f;
        #pragma unroll
        for (int c = 0; c < NCHUNK; ++c) {
            A  += ws[PA_OFF  + ((size_t)c * BB + b) * DD + k];
            Ci += ws[PCI_OFF + ((size_t)c * BB + b) * DD + k];
            Cj += ws[PCJ_OFF + ((size_t)c * BB + b) * DD + k];
        }
        const float u = ws[U0_OFF + (size_t)b * DD + k]
                      + ws[U1_OFF + (size_t)b * DD + k];
        const float v = ws[V0_OFF + (size_t)b * DD + k]
                      + ws[V1_OFF + (size_t)b * DD + k];
        s += A * u + (Ci - Cj) * v;
    }
    #pragma unroll
    for (int off = 32; off > 0; off >>= 1) s += __shfl_down(s, off, 64);

    if (l == 0) {
        float cnt = 0.f;
        #pragma unroll
        for (int c = 0; c < NCHUNK; ++c) cnt += ws[PCNT_OFF + c * BB + b];
        const float score = s + b2p[0] * cnt;   // SCALING_FACTOR == 1.0
        out[b] = 1.f / (1.f + expf(-score));
    }
}

extern "C" void kernel_launch(void* const* d_in, const int* in_sizes, int n_in,
                              void* d_out, int out_size, void* d_ws, size_t ws_size,
                              hipStream_t stream)
{
    const float* d   = (const float*)d_in[0];
    const float* si  = (const float*)d_in[1];
    const float* sj  = (const float*)d_in[2];
    const void*  mi  = d_in[3];
    const void*  mj  = d_in[4];
    const float* W1  = (const float*)d_in[5];
    const float* b1  = (const float*)d_in[6];
    const float* W2  = (const float*)d_in[7];
    const float* b2  = (const float*)d_in[8];
    float* ws  = (float*)d_ws;
    float* out = (float*)d_out;

    fused_k12<<<4096, 256, 0, stream>>>(d, si, sj, mi, mj, W1, b1, W2, ws);
    k3_final<<<BB, 64, 0, stream>>>(ws, b2, out);
}

// Round 18
// 44.113 us; speedup vs baseline: 1.1336x; 1.0992x over previous
//
#include <hip/hip_runtime.h>
#include <math.h>

#define BB 256
#define NN 1024
#define DD 128
#define NCHUNK 4
#define ROWS (NN / NCHUNK)   // 256

// workspace layout (in floats)
#define PA_OFF   0
#define PCI_OFF  (NCHUNK*BB*DD)            // 131072
#define PCJ_OFF  (2*NCHUNK*BB*DD)          // 262144
#define PCNT_OFF (3*NCHUNK*BB*DD)          // 393216
#define U0_OFF   (PCNT_OFF + NCHUNK*BB)    // 394240
#define V0_OFF   (U0_OFF + BB*DD)          // 427008
#define U1_OFF   (V0_OFF + BB*DD)          // 459776
#define V1_OFF   (U1_OFF + BB*DD)          // 492544
// total = 525312 floats = 2.10 MB

typedef _Float16 f16x8 __attribute__((ext_vector_type(8)));
typedef float    f32x4 __attribute__((ext_vector_type(4)));

// ---------------------------------------------------------------------------
// Fused kernel (r15-exact, measured best = 44.2 us): 4096 blocks =
// 3072 k1-role + 1024 k2-role ((idx&3)==1 -> k2).
//
// NOTE on the selector: idx%4==1 places all k2 blocks on XCDs 1 and 5 under
// round-robin dispatch (idx%8 in {1,5}) -- a SPATIAL PARTITION: k1 streams
// its 192 MB on 192 CUs at its pattern-limited ~4.8 TB/s aggregate (which it
// also hits on 256 CUs -- measured r9 vs r15: pattern-limited, NOT
// CU-limited), while k2's ~8 us of MFMA runs fully parallel on the other
// 64 CUs. Concurrent XCD-uniform mixing (r16, 50.0 us) and temporal
// k1-then-k2 split (r17, 48.5 us) both measured WORSE.
//
// k1 role (r9-exact body, aliased LDS): sparse masked streaming reductions.
//   role 0: P_A = sum_n (mi-mj)*d ; 1: P_Ci = sum_n mi*si ; 2: P_Cj = mj*sj
// k2 role: 64b x 64c MFMA tile of M = relu(dm@W1+b1), fused w2 contraction.
//   Bs (W1 c-half, f16, transposed [c][k]) = 17.4 KB LDS (the only LDS).
//   A-frags: per-lane direct global loads from d[:,0,:] (L2-resident) + cvt.
//   c-half partials go to U0/V0 or U1/V1; k3 sums.
// ---------------------------------------------------------------------------
__global__ __launch_bounds__(256) void fused_k12(
    const float* __restrict__ d, const float* __restrict__ si,
    const float* __restrict__ sj, const void* __restrict__ miv,
    const void* __restrict__ mjv, const float* __restrict__ W1,
    const float* __restrict__ b1, const float* __restrict__ W2,
    float* __restrict__ ws)
{
    const int idx = blockIdx.x;
    const int t   = threadIdx.x;

    // one shared buffer, aliased per role (prevents LDS sum-blowup)
    __shared__ __align__(16) char smem[17408];

    if ((idx & 3) == 1) {
        // =================== k2 role (MFMA) ===================
        const int k2id  = idx >> 2;        // 0..1023
        const int ctile = k2id & 255;      // 256 c-tiles = 128 p x 2 halves
        const int bg    = k2id >> 8;       // 0..3
        const int p     = ctile >> 1;
        const int chalf = ctile & 1;
        const int c0b   = chalf * 64;
        const int b0    = bg * 64;
        const int wid   = t >> 6;          // wave 0..3
        const int lane  = t & 63;
        const int lcol  = lane & 15;
        const int lrow  = lane >> 4;

        _Float16 (*Bs)[136] = (_Float16(*)[136])smem;   // [c][k] 17408 B

        // stage B transposed: W1[k][p*128 + c0b + c] -> Bs[c][k], f32->f16
        for (int s = t; s < 128 * 16; s += 256) {
            const int k  = s >> 4;
            const int c4 = (s & 15) * 4;
            const float4 v =
                *(const float4*)(W1 + (size_t)k * 16384 + p * 128 + c0b + c4);
            Bs[c4 + 0][k] = (_Float16)v.x;
            Bs[c4 + 1][k] = (_Float16)v.y;
            Bs[c4 + 2][k] = (_Float16)v.z;
            Bs[c4 + 3][k] = (_Float16)v.w;
        }
        __syncthreads();

        // A rows direct from global (d[:,0,:] is 128 KB, L2-resident)
        const int brow = b0 + wid * 16 + lcol;
        const float* drow = d + (size_t)brow * (NN * DD);

        f32x4 acc[4];
        #pragma unroll
        for (int n = 0; n < 4; ++n) acc[n] = (f32x4){0.f, 0.f, 0.f, 0.f};

        #pragma unroll
        for (int ks = 0; ks < 4; ++ks) {
            const int kf = ks * 32 + lrow * 8;
            const float4 a0 = *(const float4*)(drow + kf);
            const float4 a1 = *(const float4*)(drow + kf + 4);
            f16x8 afrag;
            afrag[0] = (_Float16)a0.x; afrag[1] = (_Float16)a0.y;
            afrag[2] = (_Float16)a0.z; afrag[3] = (_Float16)a0.w;
            afrag[4] = (_Float16)a1.x; afrag[5] = (_Float16)a1.y;
            afrag[6] = (_Float16)a1.z; afrag[7] = (_Float16)a1.w;
            #pragma unroll
            for (int n = 0; n < 4; ++n) {
                const f16x8 bfrag = *(const f16x8*)&Bs[n * 16 + lcol][kf];
                acc[n] = __builtin_amdgcn_mfma_f32_16x16x32_f16(
                    afrag, bfrag, acc[n], 0, 0, 0);
            }
        }

        // epilogue: relu+bias, contract c with w2a/w2b (verified C/D layout:
        // col=lane&15, row=(lane>>4)*4+reg)
        float ua[4] = {0.f, 0.f, 0.f, 0.f};
        float va[4] = {0.f, 0.f, 0.f, 0.f};
        #pragma unroll
        for (int n = 0; n < 4; ++n) {
            const int c = c0b + n * 16 + lcol;
            const float bias = b1[p * 128 + c];
            const float w2a  = W2[c];
            const float w2b  = W2[128 + c];
            #pragma unroll
            for (int reg = 0; reg < 4; ++reg) {
                const float g2 = fmaxf(acc[n][reg] + bias, 0.f);
                ua[reg] = fmaf(g2, w2a, ua[reg]);
                va[reg] = fmaf(g2, w2b, va[reg]);
            }
        }
        #pragma unroll
        for (int off = 8; off > 0; off >>= 1) {
            #pragma unroll
            for (int reg = 0; reg < 4; ++reg) {
                ua[reg] += __shfl_xor(ua[reg], off, 64);
                va[reg] += __shfl_xor(va[reg], off, 64);
            }
        }
        if (lcol == 0) {
            const size_t uo = chalf ? U1_OFF : U0_OFF;
            const size_t vo = chalf ? V1_OFF : V0_OFF;
            #pragma unroll
            for (int reg = 0; reg < 4; ++reg) {
                const int b = b0 + wid * 16 + lrow * 4 + reg;
                ws[uo + (size_t)b * DD + p] = ua[reg];
                ws[vo + (size_t)b * DD + p] = va[reg];
            }
        }
        return;
    }

    // =================== k1 role (r9-exact body, aliased LDS) ===============
    const int q4 = idx >> 2, r4 = idx & 3;
    const int k1id  = q4 * 3 + (r4 == 0 ? 0 : r4 - 1);   // 0..3071
    const int chunk = k1id & 3;
    const int b     = (k1id >> 2) & 255;
    const int role  = k1id >> 10;
    const int lane  = t & 31;   // float4 column group: cols lane*4 .. +3
    const int rg    = t >> 5;   // row group 0..7
    const int wid   = t >> 6;   // wave 0..3
    const int l64   = t & 63;

    // aliased LDS layout inside smem (total 6720 B <= 17408)
    float* s_wc   = (float*)smem;              // [256]  @0
    short* s_idx  = (short*)(smem + 1024);     // [256]  @1024
    int*   s_wcnt = (int*)(smem + 1536);       // [4]
    int*   s_woff = (int*)(smem + 1552);       // [5]
    int*   s_cnt4 = (int*)(smem + 1572);       // [4]
    int*   s_mode = (int*)(smem + 1588);       // [1]
    float (*red)[5] = (float(*)[5])(smem + 1600);  // [256][5]

    // ---- mask dtype auto-detect (bool bytes vs int32) ----
    if (t == 0) *s_mode = 0;
    __syncthreads();
    {
        const unsigned int* a = (const unsigned int*)miv;
        const unsigned int* c = (const unsigned int*)mjv;
        if ((a[t] | c[t]) > 1u) *s_mode = 1;  // bytes of 0/1 packed in a word
    }
    __syncthreads();
    const bool bytes_mode = (*s_mode != 0);

    const int    n0      = chunk * ROWS;
    const size_t rowbase = (size_t)b * NN;

    float w;
    {
        const size_t m = rowbase + (size_t)(n0 + t);
        float fi, fj;
        if (bytes_mode) {
            fi = (float)((const unsigned char*)miv)[m];
            fj = (float)((const unsigned char*)mjv)[m];
        } else {
            fi = (float)((const int*)miv)[m];
            fj = (float)((const int*)mjv)[m];
        }
        w = (role == 0) ? (fi - fj) : ((role == 1) ? fi : fj);
        if (role == 0) {
            const unsigned long long bi = __ballot(fi != 0.f);
            const unsigned long long bj = __ballot(fj != 0.f);
            if (l64 == 0) s_cnt4[wid] = __popcll(bi) - __popcll(bj);
        }
    }
    const bool keep = (w != 0.f);
    const unsigned long long ball = __ballot(keep);
    const int prefix = __popcll(ball & ((1ull << l64) - 1ull));
    if (l64 == 0) s_wcnt[wid] = __popcll(ball);
    __syncthreads();
    if (t == 0) {
        int a0 = 0;
        #pragma unroll
        for (int ww = 0; ww < 4; ++ww) { s_woff[ww] = a0; a0 += s_wcnt[ww]; }
        s_woff[4] = a0;
        if (role == 0)
            ws[PCNT_OFF + chunk * BB + b] =
                (float)(s_cnt4[0] + s_cnt4[1] + s_cnt4[2] + s_cnt4[3]);
    }
    __syncthreads();
    const int K    = s_woff[4];
    const int Kpad = (K + 31) & ~31;
    if (keep) {
        const int pos = s_woff[wid] + prefix;
        s_idx[pos] = (short)t;
        s_wc[pos]  = w;
    }
    for (int p = K + t; p < Kpad; p += 256) { s_idx[p] = 0; s_wc[p] = 0.f; }
    __syncthreads();

    const float* src = (role == 0) ? d : ((role == 1) ? si : sj);
    const size_t cbase = (rowbase + (size_t)n0) * (size_t)DD
                       + (size_t)lane * 4;

    float acc[4] = {0.f, 0.f, 0.f, 0.f};

    for (int i = 0; i < Kpad; i += 32) {
        int   r[4];
        float wv[4];
        #pragma unroll
        for (int u = 0; u < 4; ++u) {
            const int p = i + u * 8 + rg;
            r[u]  = s_idx[p];      // broadcast within row-group
            wv[u] = s_wc[p];
        }
        float4 v[4];
        #pragma unroll
        for (int u = 0; u < 4; ++u)
            v[u] = *(const float4*)(src + cbase + (size_t)r[u] * DD);
        #pragma unroll
        for (int u = 0; u < 4; ++u) {
            acc[0] = fmaf(wv[u], v[u].x, acc[0]);
            acc[1] = fmaf(wv[u], v[u].y, acc[1]);
            acc[2] = fmaf(wv[u], v[u].z, acc[2]);
            acc[3] = fmaf(wv[u], v[u].w, acc[3]);
        }
    }

    // ---- reduce the 8 row-groups (t strides of 32); [5] breaks bank stride
    #pragma unroll
    for (int i = 0; i < 4; ++i) red[t][i] = acc[i];
    __syncthreads();
    if (t < 128) {
        #pragma unroll
        for (int i = 0; i < 4; ++i) red[t][i] += red[t + 128][i];
    }
    __syncthreads();
    if (t < 64) {
        #pragma unroll
        for (int i = 0; i < 4; ++i) red[t][i] += red[t + 64][i];
    }
    __syncthreads();
    if (t < 32) {
        #pragma unroll
        for (int i = 0; i < 4; ++i) red[t][i] += red[t + 32][i];
        const size_t poff = ((role == 0) ? PA_OFF : ((role == 1) ? PCI_OFF
                                                                 : PCJ_OFF))
                          + ((size_t)chunk * BB + b) * DD;
        float* P = ws + poff;
        #pragma unroll
        for (int i = 0; i < 4; ++i) P[t * 4 + i] = red[t][i];
    }
}

// ---------------------------------------------------------------------------
// Kernel 3: per-batch score assembly + sigmoid.
//   out[b] = sigmoid( Adiff·(u0+u1) + (Ci-Cj)·(v0+v1) + b2*cntdiff )
// grid = 256, block = 64 (one wave per batch).
// ---------------------------------------------------------------------------
__global__ __launch_bounds__(64) void k3_final(
    const float* __restrict__ ws, const float* __restrict__ b2p,
    float* __restrict__ out)
{
    const int b = blockIdx.x;
    const int l = threadIdx.x;

    float s = 0.f;
    #pragma unroll
    for (int rep = 0; rep < 2; ++rep) {
        const int k = l + rep * 64;
        float A = 0.f, Ci = 0.f, Cj = 0.f;
        #pragma unroll
        for (int c = 0; c < NCHUNK; ++c) {
            A  += ws[PA_OFF  + ((size_t)c * BB + b) * DD + k];
            Ci += ws[PCI_OFF + ((size_t)c * BB + b) * DD + k];
            Cj += ws[PCJ_OFF + ((size_t)c * BB + b) * DD + k];
        }
        const float u = ws[U0_OFF + (size_t)b * DD + k]
                      + ws[U1_OFF + (size_t)b * DD + k];
        const float v = ws[V0_OFF + (size_t)b * DD + k]
                      + ws[V1_OFF + (size_t)b * DD + k];
        s += A * u + (Ci - Cj) * v;
    }
    #pragma unroll
    for (int off = 32; off > 0; off >>= 1) s += __shfl_down(s, off, 64);

    if (l == 0) {
        float cnt = 0.f;
        #pragma unroll
        for (int c = 0; c < NCHUNK; ++c) cnt += ws[PCNT_OFF + c * BB + b];
        const float score = s + b2p[0] * cnt;   // SCALING_FACTOR == 1.0
        out[b] = 1.f / (1.f + expf(-score));
    }
}

extern "C" void kernel_launch(void* const* d_in, const int* in_sizes, int n_in,
                              void* d_out, int out_size, void* d_ws, size_t ws_size,
                              hipStream_t stream)
{
    const float* d   = (const float*)d_in[0];
    const float* si  = (const float*)d_in[1];
    const float* sj  = (const float*)d_in[2];
    const void*  mi  = d_in[3];
    const void*  mj  = d_in[4];
    const float* W1  = (const float*)d_in[5];
    const float* b1  = (const float*)d_in[6];
    const float* W2  = (const float*)d_in[7];
    const float* b2  = (const float*)d_in[8];
    float* ws  = (float*)d_ws;
    float* out = (float*)d_out;

    fused_k12<<<4096, 256, 0, stream>>>(d, si, sj, mi, mj, W1, b1, W2, ws);
    k3_final<<<BB, 64, 0, stream>>>(ws, b2, out);
}